// Round 10
// baseline (217.848 us; speedup 1.0000x reference)
//
#include <hip/hip_runtime.h>
#include <hip/hip_fp16.h>

#define BB 32
#define HH 512
#define WW 512
#define NQROW (WW / 4)            // 128 float4 per row
#define NPIX_F 8388608.0f         // 32*512*512
#define QPAD 4

// ---- fused kernel geometry ----
#define RF 16                     // output rows per wave
#define NSTRF (HH / RF)           // 32 stripes
#define NBF (BB * NSTRF * 2)      // 2048 blocks (1 wave each)
#define NROWSF (RF + 30)          // 46 input rows per stripe
#define CQH 64                    // owned quads per column half (256 cols)
#define NQPH (CQH + 2 * QPAD)     // 72 quads incl halo
#define WS_NEED_F ((size_t)NBF * 16)   // 32 KiB of float4 partials

__device__ __forceinline__ void elemwise4(const float h0, const float h1,
                                          const float h2, const float h3,
                                          const float4 t, const float4 p,
                                          float& a_bce, float& a_w,
                                          float& a_i, float& a_u)
{
    const float hv[4] = {h0, h1, h2, h3};
    const float tv[4] = {t.x, t.y, t.z, t.w};
    const float pv[4] = {p.x, p.y, p.z, p.w};
    const float inv961 = (1.0f / 961.0f);
    #pragma unroll
    for (int j = 0; j < 4; ++j) {
        const float ap = hv[j] * inv961;
        const float w  = fmaf(5.0f, fabsf(ap - tv[j]), 1.0f);
        const float pr = pv[j];
        const float ea = __expf(-fabsf(pr));                  // exp(-|pr|)
        const float iv = __builtin_amdgcn_rcpf(1.0f + ea);
        const float pp = (pr >= 0.0f) ? iv : (1.0f - iv);     // sigmoid
        const float sp = fmaxf(pr, 0.0f) + __logf(1.0f + ea); // softplus
        a_bce += sp - pr * tv[j];
        a_w   += w;
        a_i   += pp * tv[j] * w;
        a_u   += (pp + tv[j]) * w;
    }
}

// ---- Fused single pass, issue-tuned:
//  * FULL UNROLL: pipeline shifts become register renames (no v_mov chains),
//    svr indices become compile-time (no dynamic anything in registers)
//  * SoA LDS (all b32, lane-stride 4B -> 2-way aliasing = free on gfx950)
//  * double-buffered exchange arrays so step k+1 writes overlap step k reads
//  * h-row exit history as packed fp16 in LDS (add rounded / subtract SAME
//    rounded value -> exact cancellation; validated rounds 1-9)
__global__ __launch_bounds__(64, 2)
void fused_rows_kernel(const float* __restrict__ pred,
                       const float* __restrict__ targ,
                       float4* __restrict__ part)
{
    const int lane = threadIdx.x;
    const int bi = blockIdx.x;                 // 2048
    const int halfc  = bi & 1;
    const int stripe = (bi >> 1) & (NSTRF - 1);
    const int b      = bi >> 6;
    const int r0  = stripe * RF;
    const int cq0 = halfc * CQH;
    const int q   = cq0 + lane;                // owned quad (global col/4)

    // SoA, conflict-free (4B lane stride), double-buffered on step parity
    __shared__ float ex[2][NQPH], ey[2][NQPH], ez[2][NQPH], ew[2][NQPH];
    __shared__ float lq[2][NQPH];
    __shared__ unsigned svx[RF][64], svy[RF][64];   // packed fp16 h-rows, 8 KB

    const float4* t4 = (const float4*)(targ + (size_t)b * HH * WW);
    const float4* p4 = (const float4*)(pred + (size_t)b * HH * WW);
    const float4 Z4 = make_float4(0.f, 0.f, 0.f, 0.f);

    // halo quads handled by lanes 0..7 (slots 0..3 and 68..71; OOB -> zeros)
    const int hq = (lane < 4) ? (cq0 - QPAD + lane) : (cq0 + CQH + (lane - 4));
    const bool hq_ok = (lane < 8) && (hq >= 0) && (hq < NQROW);
    const int hslot = (lane < 4) ? lane : (CQH + QPAD + (lane - 4));

    auto ldo = [&](int k) -> float4 {          // owned quad, input row r0-15+k
        const int yy = r0 - 15 + k;
        return (k < NROWSF && yy >= 0 && yy < HH)
                   ? t4[(size_t)yy * NQROW + q] : Z4;
    };
    auto ldh = [&](int k) -> float4 {          // halo quad
        const int yy = r0 - 15 + k;
        return (k < NROWSF && hq_ok && yy >= 0 && yy < HH)
                   ? t4[(size_t)yy * NQROW + hq] : Z4;
    };

    // prefetch pipelines: raw rows depth 4 (HBM), t/p depth 2 (L2/L3-hot)
    float4 e0 = ldo(0), e1 = ldo(1), e2 = ldo(2), e3 = ldo(3);
    float4 g0 = ldh(0), g1 = ldh(1), g2 = ldh(2), g3 = ldh(3);
    float4 t0 = Z4, t1 = Z4, p0 = Z4, p1 = Z4;

    float v0 = 0.f, v1 = 0.f, v2 = 0.f, v3 = 0.f;
    float a_bce = 0.f, a_w = 0.f, a_i = 0.f, a_u = 0.f;

    #pragma unroll
    for (int k = 0; k < NROWSF; ++k) {         // input row r0-15+k
        const float4 e  = e0;  e0 = e1; e1 = e2; e2 = e3; e3 = ldo(k + 4);
        const float4 eh = g0;  g0 = g1; g1 = g2; g2 = g3; g3 = ldh(k + 4);

        // t/p: issue for output j=k-28 here, consume 2 steps later (k=j+30)
        const float4 tc = t0;  t0 = t1;
        const float4 pc = p0;  p0 = p1;
        if (k >= 28 && k < 28 + RF) {
            const size_t off = (size_t)(r0 + (k - 28)) * NQROW + q;
            t1 = t4[off];
            p1 = p4[off];
        }

        const int bf = k & 1;                  // compile-time under unroll
        ex[bf][QPAD + lane] = e.x;
        ey[bf][QPAD + lane] = e.y;
        ez[bf][QPAD + lane] = e.z;
        ew[bf][QPAD + lane] = e.w;
        lq[bf][QPAD + lane] = e.x + e.y + e.z + e.w;
        if (lane < 8) {
            ex[bf][hslot] = eh.x;
            ey[bf][hslot] = eh.y;
            ez[bf][hslot] = eh.z;
            ew[bf][hslot] = eh.w;
            lq[bf][hslot] = eh.x + eh.y + eh.z + eh.w;
        }
        __builtin_amdgcn_wave_barrier();       // writes before reads (sched)

        // horizontal 31-sums for owned cols 4q..4q+3 (pattern verified r1-r9)
        float F = 0.f;
        #pragma unroll
        for (int d = -3; d <= 3; ++d) F += lq[bf][QPAD + lane + d];
        const int iL = lane;                   // quad q-4
        const int iU = lane + 2 * QPAD;        // quad q+4
        const float Ly = ey[bf][iL], Lz = ez[bf][iL], Lw = ew[bf][iL];
        const float Ux = ex[bf][iU], Uy = ey[bf][iU], Uz = ez[bf][iU];
        const float hs0 = F + Ly + Lz + Lw;
        const float hs1 = F + Lz + Lw + Ux;
        const float hs2 = F + Lw + Ux + Uy;
        const float hs3 = F + Ux + Uy + Uz;

        if (k < RF) {
            // quantize once; add the SAME rounded value subtracted at exit
            const __half2 q01 = __floats2half2_rn(hs0, hs1);
            const __half2 q23 = __floats2half2_rn(hs2, hs3);
            svx[k][lane] = __builtin_bit_cast(unsigned int, q01);
            svy[k][lane] = __builtin_bit_cast(unsigned int, q23);
            const float2 f01 = __half22float2(q01);
            const float2 f23 = __half22float2(q23);
            v0 += f01.x; v1 += f01.y; v2 += f23.x; v3 += f23.y;
        } else {
            v0 += hs0; v1 += hs1; v2 += hs2; v3 += hs3;
        }

        if (k >= 30) {
            elemwise4(v0, v1, v2, v3, tc, pc, a_bce, a_w, a_i, a_u);
            const float2 f01 = __half22float2(
                __builtin_bit_cast(__half2, svx[k - 30][lane]));
            const float2 f23 = __half22float2(
                __builtin_bit_cast(__half2, svy[k - 30][lane]));
            v0 -= f01.x; v1 -= f01.y; v2 -= f23.x; v3 -= f23.y;
        }
    }

    #pragma unroll
    for (int off = 32; off > 0; off >>= 1) {
        a_bce += __shfl_down(a_bce, off, 64);
        a_w   += __shfl_down(a_w,   off, 64);
        a_i   += __shfl_down(a_i,   off, 64);
        a_u   += __shfl_down(a_u,   off, 64);
    }
    if (lane == 0) part[bi] = make_float4(a_bce, a_w, a_i, a_u);
}

// ---- Finalize: 64 partials per image -> per-image sums -> scalar --------
__global__ __launch_bounds__(1024)
void finalize3_kernel(const float4* __restrict__ part, float* __restrict__ out)
{
    const int lane = threadIdx.x & 63;
    const int w    = threadIdx.x >> 6;         // 16 waves, 2 images each
    __shared__ float4 sums[BB];

    #pragma unroll
    for (int s = 0; s < 2; ++s) {
        const int img = w * 2 + s;
        float4 acc = part[img * 64 + lane];    // exactly one partial per lane
        #pragma unroll
        for (int off = 32; off > 0; off >>= 1) {
            acc.x += __shfl_down(acc.x, off, 64);
            acc.y += __shfl_down(acc.y, off, 64);
            acc.z += __shfl_down(acc.z, off, 64);
            acc.w += __shfl_down(acc.w, off, 64);
        }
        if (lane == 0) sums[img] = acc;
    }
    __syncthreads();

    if (w == 0) {
        float bsum = (lane < BB) ? sums[lane].x : 0.f;
        #pragma unroll
        for (int off = 32; off > 0; off >>= 1) bsum += __shfl_down(bsum, off, 64);
        const float bce = __shfl(bsum, 0, 64) * (1.0f / NPIX_F);

        float val = 0.f;
        if (lane < BB) {
            const float wsum  = sums[lane].y;
            const float inter = sums[lane].z;
            const float uni   = sums[lane].w;
            const float w_bce = (wsum * bce + 1e-8f) / (wsum + 1e-8f);
            const float w_iou = 1.0f - (inter + 1.0f + 1e-8f) / (uni - inter + 1.0f + 1e-8f);
            val = w_bce + w_iou;
        }
        #pragma unroll
        for (int off = 32; off > 0; off >>= 1) val += __shfl_down(val, off, 64);
        if (lane == 0) out[0] = val * (1.0f / BB);
    }
}

// ================= fallback (validated round-2 fused path) ===============
#define PADK 15
#define RROWS 32
#define NSTRIPES (HH / RROWS)
#define NCH 2
#define COLS (WW / NCH)
#define CQ (COLS / 4)
#define FNQP (CQ + 2 * QPAD)
#define NSTEPS (RROWS + 2 * PADK)

__global__ __launch_bounds__(64)
void fused_pool_loss_kernel(const float* __restrict__ pred,
                            const float* __restrict__ targ,
                            float* __restrict__ ws)
{
    const int lane = threadIdx.x;
    const int bi   = blockIdx.x;
    const int half   = bi & 1;
    const int stripe = (bi >> 1) & (NSTRIPES - 1);
    const int b      = bi >> 5;
    const int r0  = stripe * RROWS;
    const int cq0 = half * CQ;

    __shared__ __half2 ring[31][2][64];
    __shared__ float4  ebuf[2][FNQP];
    __shared__ float   locq[2][FNQP];

    {
        const __half2 z2 = __floats2half2_rn(0.f, 0.f);
        __half2* rp = &ring[0][0][0];
        for (int i = lane; i < 31 * 2 * 64; i += 64) rp[i] = z2;
    }
    __builtin_amdgcn_wave_barrier();

    const float4* targ4 = (const float4*)(targ + (size_t)b * HH * WW);
    const float4* pred4 = (const float4*)(pred + (size_t)b * HH * WW);
    const float4 Z4 = make_float4(0.f, 0.f, 0.f, 0.f);

    const int hq = (lane < 4) ? (cq0 - QPAD + lane) : (cq0 + CQ + (lane - 4));
    const bool hq_ok = (lane < 8) && (hq >= 0) && (hq < NQROW);
    const int hslot = (lane < 4) ? lane : (CQ + QPAD + (lane - 4));

    auto ld_row = [&](int step, float4& m, float4& h) {
        m = Z4; h = Z4;
        const int yy = r0 - PADK + step;
        if (step < NSTEPS && yy >= 0 && yy < HH) {
            const float4* rp = targ4 + (size_t)yy * NQROW;
            m = rp[cq0 + lane];
            if (hq_ok) h = rp[hq];
        }
    };

    float vacc0 = 0.f, vacc1 = 0.f, vacc2 = 0.f, vacc3 = 0.f;
    float a_bce = 0.f, a_w = 0.f, a_i = 0.f, a_u = 0.f;
    int slot = 0;

    float4 e_p0, e_p1, h_p0, h_p1;
    ld_row(0, e_p0, h_p0);
    ld_row(1, e_p1, h_p1);
    float4 t_p0 = Z4, t_p1 = Z4, p_p0 = Z4, p_p1 = Z4;

    for (int step = 0; step < NSTEPS; ++step) {
        const float4 e  = e_p0;  e_p0 = e_p1;
        const float4 eh = h_p0;  h_p0 = h_p1;
        ld_row(step + 2, e_p1, h_p1);

        const float4 tcur = t_p0, pcur = p_p0;
        t_p0 = t_p1; p_p0 = p_p1;
        {
            const int s2 = step + 2;
            if (s2 >= 2 * PADK && s2 < NSTEPS) {
                const size_t off = (size_t)(r0 + (s2 - 2 * PADK)) * NQROW + cq0 + lane;
                t_p1 = targ4[off];
                p_p1 = pred4[off];
            }
        }

        const int bf = step & 1;
        ebuf[bf][QPAD + lane] = e;
        locq[bf][QPAD + lane] = e.x + e.y + e.z + e.w;
        if (lane < 8) {
            ebuf[bf][hslot] = eh;
            locq[bf][hslot] = eh.x + eh.y + eh.z + eh.w;
        }
        __builtin_amdgcn_wave_barrier();

        float F = 0.f;
        #pragma unroll
        for (int k = -3; k <= 3; ++k) F += locq[bf][lane + QPAD + k];
        const float4 L = ebuf[bf][lane];
        const float4 U = ebuf[bf][lane + 2 * QPAD];
        const float h0 = F + L.y + L.z + L.w;
        const float h1 = F + L.z + L.w + U.x;
        const float h2 = F + L.w + U.x + U.y;
        const float h3 = F + U.x + U.y + U.z;

        const __half2 n01 = __floats2half2_rn(h0, h1);
        const __half2 n23 = __floats2half2_rn(h2, h3);
        const __half2 o01 = ring[slot][0][lane];
        const __half2 o23 = ring[slot][1][lane];
        ring[slot][0][lane] = n01;
        ring[slot][1][lane] = n23;
        const float2 nf01 = __half22float2(n01), nf23 = __half22float2(n23);
        const float2 of01 = __half22float2(o01), of23 = __half22float2(o23);
        vacc0 += nf01.x - of01.x;
        vacc1 += nf01.y - of01.y;
        vacc2 += nf23.x - of23.x;
        vacc3 += nf23.y - of23.y;
        slot = (slot == 30) ? 0 : (slot + 1);

        if (step >= 2 * PADK) {
            elemwise4(vacc0, vacc1, vacc2, vacc3, tcur, pcur, a_bce, a_w, a_i, a_u);
        }
    }

    #pragma unroll
    for (int off = 32; off > 0; off >>= 1) {
        a_bce += __shfl_down(a_bce, off, 64);
        a_w   += __shfl_down(a_w,   off, 64);
        a_i   += __shfl_down(a_i,   off, 64);
        a_u   += __shfl_down(a_u,   off, 64);
    }
    if (lane == 0) {
        atomicAdd(&ws[0],      a_bce);
        atomicAdd(&ws[1 + b],  a_w);
        atomicAdd(&ws[33 + b], a_i);
        atomicAdd(&ws[65 + b], a_u);
    }
}

__global__ void finalize_kernel(const float* __restrict__ ws, float* __restrict__ out)
{
    const int i = threadIdx.x;
    float val = 0.f;
    if (i < BB) {
        const float bce   = ws[0] * (1.0f / NPIX_F);
        const float wsum  = ws[1 + i];
        const float inter = ws[33 + i];
        const float uni   = ws[65 + i];
        const float w_bce = (wsum * bce + 1e-8f) / (wsum + 1e-8f);
        const float w_iou = 1.0f - (inter + 1.0f + 1e-8f) / (uni - inter + 1.0f + 1e-8f);
        val = w_bce + w_iou;
    }
    #pragma unroll
    for (int off = 32; off > 0; off >>= 1) val += __shfl_down(val, off, 64);
    if (i == 0) out[0] = val * (1.0f / BB);
}

extern "C" void kernel_launch(void* const* d_in, const int* in_sizes, int n_in,
                              void* d_out, int out_size, void* d_ws, size_t ws_size,
                              hipStream_t stream)
{
    (void)in_sizes; (void)n_in; (void)out_size;
    const float* pred = (const float*)d_in[0];   // y_pred
    const float* targ = (const float*)d_in[1];   // y_target
    float* out = (float*)d_out;

    if (ws_size >= WS_NEED_F) {
        float4* part = (float4*)d_ws;
        hipLaunchKernelGGL(fused_rows_kernel, dim3(NBF), dim3(64), 0, stream,
                           pred, targ, part);
        hipLaunchKernelGGL(finalize3_kernel, dim3(1), dim3(1024), 0, stream,
                           part, out);
    } else {
        float* ws = (float*)d_ws;
        hipMemsetAsync(ws, 0, 97 * sizeof(float), stream);
        hipLaunchKernelGGL(fused_pool_loss_kernel,
                           dim3(BB * NSTRIPES * NCH), dim3(64), 0, stream,
                           pred, targ, ws);
        hipLaunchKernelGGL(finalize_kernel, dim3(1), dim3(64), 0, stream, ws, out);
    }
}

// Round 11
// 136.618 us; speedup vs baseline: 1.5946x; 1.5946x over previous
//
#include <hip/hip_runtime.h>
#include <hip/hip_fp16.h>

#define BB 32
#define HH 512
#define WW 512
#define NQROW (WW / 4)            // 128 float4 per row
#define NPIX_F 8388608.0f         // 32*512*512
#define QPAD 4
#define NQP (NQROW + 2 * QPAD)    // 136

// ---- two-pass row-parallel geometry ----
#define NB_A (BB * HH)            // 16384 pass-A blocks (1 wave = 1 row)
#define RB 4                      // output rows per pass-B wave
#define NGRP (HH / RB)            // 128 row-groups per image
#define NB_B (BB * NGRP)          // 4096 pass-B blocks (1 wave each)
#define PART_OFF 0
#define H_OFF 65536               // after 4096 float4 partials
#define WS_NEED2 ((size_t)H_OFF + (size_t)BB * HH * WW * 2)   // ~16.8 MB

__device__ __forceinline__ void elemwise4(const float h0, const float h1,
                                          const float h2, const float h3,
                                          const float4 t, const float4 p,
                                          float& a_bce, float& a_w,
                                          float& a_i, float& a_u)
{
    const float hv[4] = {h0, h1, h2, h3};
    const float tv[4] = {t.x, t.y, t.z, t.w};
    const float pv[4] = {p.x, p.y, p.z, p.w};
    const float inv961 = (1.0f / 961.0f);
    #pragma unroll
    for (int j = 0; j < 4; ++j) {
        const float ap = hv[j] * inv961;
        const float w  = fmaf(5.0f, fabsf(ap - tv[j]), 1.0f);
        const float pr = pv[j];
        const float ea = __expf(-fabsf(pr));                  // exp(-|pr|)
        const float iv = __builtin_amdgcn_rcpf(1.0f + ea);
        const float pp = (pr >= 0.0f) ? iv : (1.0f - iv);     // sigmoid
        const float sp = fmaxf(pr, 0.0f) + __logf(1.0f + ea); // softplus
        a_bce += sp - pr * tv[j];
        a_w   += w;
        a_i   += pp * tv[j] * w;
        a_u   += (pp + tv[j]) * w;
    }
}

// ---- Pass A: horizontal 31-sum per row -> H fp16. One wave per row,
// fully parallel (16 waves/SIMD). LDS exchange = r6-validated pattern,
// SoA layout (4B lane stride -> conflict-free, validated r10).
__global__ __launch_bounds__(64)
void hsum_kernel(const float* __restrict__ targ, __half* __restrict__ H)
{
    const int lane = threadIdx.x;
    const int gr = blockIdx.x;                 // global row id (b*512+y)
    const size_t rowoff = (size_t)gr * WW;

    __shared__ float ex[NQP], ey[NQP], ez[NQP], ew[NQP], lq[NQP];

    const float4* t4 = (const float4*)(targ + rowoff);
    const float4 tA = t4[lane];                // quad lane   (cols 4l..)
    const float4 tB = t4[64 + lane];           // quad 64+l

    if (lane < 2 * QPAD) {                     // zero x-halo pads (img edge)
        const int idx = (lane < QPAD) ? lane : (NQROW + lane);
        ex[idx] = 0.f; ey[idx] = 0.f; ez[idx] = 0.f; ew[idx] = 0.f;
        lq[idx] = 0.f;
    }
    ex[QPAD + lane] = tA.x;  ey[QPAD + lane] = tA.y;
    ez[QPAD + lane] = tA.z;  ew[QPAD + lane] = tA.w;
    lq[QPAD + lane] = tA.x + tA.y + tA.z + tA.w;
    ex[QPAD + 64 + lane] = tB.x;  ey[QPAD + 64 + lane] = tB.y;
    ez[QPAD + 64 + lane] = tB.z;  ew[QPAD + 64 + lane] = tB.w;
    lq[QPAD + 64 + lane] = tB.x + tB.y + tB.z + tB.w;
    __builtin_amdgcn_wave_barrier();           // single-wave LDS exchange

    __half* Hr = H + rowoff;
    #pragma unroll
    for (int hf = 0; hf < 2; ++hf) {
        const int q = hf * 64 + lane;          // owned quad
        float F = 0.f;
        #pragma unroll
        for (int d = -3; d <= 3; ++d) F += lq[QPAD + q + d];
        const int iL = QPAD + q - 4, iU = QPAD + q + 4;
        const float Ly = ey[iL], Lz = ez[iL], Lw = ew[iL];
        const float Ux = ex[iU], Uy = ey[iU], Uz = ez[iU];
        const float h0 = F + Ly + Lz + Lw;     // col 4q: [4q-15..4q+15]
        const float h1 = F + Lz + Lw + Ux;
        const float h2 = F + Lw + Ux + Uy;
        const float h3 = F + Ux + Uy + Uz;
        const __half2 q01 = __floats2half2_rn(h0, h1);
        const __half2 q23 = __floats2half2_rn(h2, h3);
        uint2 pk;
        pk.x = __builtin_bit_cast(unsigned int, q01);
        pk.y = __builtin_bit_cast(unsigned int, q23);
        *(uint2*)(Hr + 4 * q) = pk;            // cols 4q..4q+3
    }
}

// ---- Pass B: brute 31-row vertical sum of H (independent loads, no
// serial chain) + elementwise + per-block partial. One wave per 4 output
// rows (4 waves/SIMD). Lane owns cols 8l..8l+7.
__global__ __launch_bounds__(64)
void vsum_loss_kernel(const float* __restrict__ pred,
                      const float* __restrict__ targ,
                      const __half* __restrict__ H,
                      float4* __restrict__ part)
{
    const int lane = threadIdx.x;
    const int bi = blockIdx.x;                 // 4096
    const int b  = bi >> 7;                    // image
    const int y0 = (bi & (NGRP - 1)) * RB;     // first output row
    const size_t imgoff = (size_t)b * HH * WW;

    const __half* Hb = H + imgoff;
    const uint4 ZU = make_uint4(0u, 0u, 0u, 0u);   // 8 x +0.0h

    auto ldH = [&](int y) -> uint4 {           // wave-uniform guard
        return (y >= 0 && y < HH)
                   ? ((const uint4*)(Hb + (size_t)y * WW))[lane] : ZU;
    };

    float a0 = 0.f, a1 = 0.f, a2 = 0.f, a3 = 0.f;
    float a4 = 0.f, a5 = 0.f, a6 = 0.f, a7 = 0.f;
    auto addH = [&](uint4 v) {
        const float2 f01 = __half22float2(__builtin_bit_cast(__half2, v.x));
        const float2 f23 = __half22float2(__builtin_bit_cast(__half2, v.y));
        const float2 f45 = __half22float2(__builtin_bit_cast(__half2, v.z));
        const float2 f67 = __half22float2(__builtin_bit_cast(__half2, v.w));
        a0 += f01.x; a1 += f01.y; a2 += f23.x; a3 += f23.y;
        a4 += f45.x; a5 += f45.y; a6 += f67.x; a7 += f67.y;
    };
    auto subH = [&](uint4 v) {
        const float2 f01 = __half22float2(__builtin_bit_cast(__half2, v.x));
        const float2 f23 = __half22float2(__builtin_bit_cast(__half2, v.y));
        const float2 f45 = __half22float2(__builtin_bit_cast(__half2, v.z));
        const float2 f67 = __half22float2(__builtin_bit_cast(__half2, v.w));
        a0 -= f01.x; a1 -= f01.y; a2 -= f23.x; a3 -= f23.y;
        a4 -= f45.x; a5 -= f45.y; a6 -= f67.x; a7 -= f67.y;
    };

    // 31-row window for output row y0 (8 loads in flight per batch —
    // bounded MLP, nothing for the scheduler to spill)
    #pragma unroll 8
    for (int i = 0; i < 31; ++i) addH(ldH(y0 - 15 + i));

    // t/p for the 4 output rows: cols 8l..8l+7 = quads 2l, 2l+1
    const float4* t4r = (const float4*)(targ + imgoff);
    const float4* p4r = (const float4*)(pred + imgoff);
    float4 tl[RB], th[RB], pl[RB], ph[RB];
    #pragma unroll
    for (int r = 0; r < RB; ++r) {
        const size_t ro = (size_t)(y0 + r) * NQROW;
        tl[r] = t4r[ro + 2 * lane];
        th[r] = t4r[ro + 2 * lane + 1];
        pl[r] = p4r[ro + 2 * lane];
        ph[r] = p4r[ro + 2 * lane + 1];
    }

    float a_bce = 0.f, a_w = 0.f, a_i = 0.f, a_u = 0.f;
    #pragma unroll
    for (int r = 0; r < RB; ++r) {
        if (r > 0) {                           // slide window down one row
            addH(ldH(y0 + 15 + r));
            subH(ldH(y0 - 16 + r));
        }
        elemwise4(a0, a1, a2, a3, tl[r], pl[r], a_bce, a_w, a_i, a_u);
        elemwise4(a4, a5, a6, a7, th[r], ph[r], a_bce, a_w, a_i, a_u);
    }

    #pragma unroll
    for (int off = 32; off > 0; off >>= 1) {
        a_bce += __shfl_down(a_bce, off, 64);
        a_w   += __shfl_down(a_w,   off, 64);
        a_i   += __shfl_down(a_i,   off, 64);
        a_u   += __shfl_down(a_u,   off, 64);
    }
    if (lane == 0) part[bi] = make_float4(a_bce, a_w, a_i, a_u);
}

// ---- Finalize: 128 partials per image -> per-image sums -> scalar ------
__global__ __launch_bounds__(1024)
void finalize4_kernel(const float4* __restrict__ part, float* __restrict__ out)
{
    const int lane = threadIdx.x & 63;
    const int w    = threadIdx.x >> 6;         // 16 waves, 2 images each
    __shared__ float4 sums[BB];

    #pragma unroll
    for (int s = 0; s < 2; ++s) {
        const int img = w * 2 + s;
        const int base = img * 128;
        const float4 u = part[base + lane];
        const float4 v = part[base + 64 + lane];
        float4 acc = make_float4(u.x + v.x, u.y + v.y, u.z + v.z, u.w + v.w);
        #pragma unroll
        for (int off = 32; off > 0; off >>= 1) {
            acc.x += __shfl_down(acc.x, off, 64);
            acc.y += __shfl_down(acc.y, off, 64);
            acc.z += __shfl_down(acc.z, off, 64);
            acc.w += __shfl_down(acc.w, off, 64);
        }
        if (lane == 0) sums[img] = acc;
    }
    __syncthreads();

    if (w == 0) {
        float bsum = (lane < BB) ? sums[lane].x : 0.f;
        #pragma unroll
        for (int off = 32; off > 0; off >>= 1) bsum += __shfl_down(bsum, off, 64);
        const float bce = __shfl(bsum, 0, 64) * (1.0f / NPIX_F);

        float val = 0.f;
        if (lane < BB) {
            const float wsum  = sums[lane].y;
            const float inter = sums[lane].z;
            const float uni   = sums[lane].w;
            const float w_bce = (wsum * bce + 1e-8f) / (wsum + 1e-8f);
            const float w_iou = 1.0f - (inter + 1.0f + 1e-8f) / (uni - inter + 1.0f + 1e-8f);
            val = w_bce + w_iou;
        }
        #pragma unroll
        for (int off = 32; off > 0; off >>= 1) val += __shfl_down(val, off, 64);
        if (lane == 0) out[0] = val * (1.0f / BB);
    }
}

// ================= fallback (validated round-2 fused path) ===============
#define PADK 15
#define RROWS 32
#define NSTRIPES (HH / RROWS)
#define NCH 2
#define COLS (WW / NCH)
#define CQ (COLS / 4)
#define FNQP (CQ + 2 * QPAD)
#define NSTEPS (RROWS + 2 * PADK)

__global__ __launch_bounds__(64)
void fused_pool_loss_kernel(const float* __restrict__ pred,
                            const float* __restrict__ targ,
                            float* __restrict__ ws)
{
    const int lane = threadIdx.x;
    const int bi   = blockIdx.x;
    const int half   = bi & 1;
    const int stripe = (bi >> 1) & (NSTRIPES - 1);
    const int b      = bi >> 5;
    const int r0  = stripe * RROWS;
    const int cq0 = half * CQ;

    __shared__ __half2 ring[31][2][64];
    __shared__ float4  ebuf[2][FNQP];
    __shared__ float   locq[2][FNQP];

    {
        const __half2 z2 = __floats2half2_rn(0.f, 0.f);
        __half2* rp = &ring[0][0][0];
        for (int i = lane; i < 31 * 2 * 64; i += 64) rp[i] = z2;
    }
    __builtin_amdgcn_wave_barrier();

    const float4* targ4 = (const float4*)(targ + (size_t)b * HH * WW);
    const float4* pred4 = (const float4*)(pred + (size_t)b * HH * WW);
    const float4 Z4 = make_float4(0.f, 0.f, 0.f, 0.f);

    const int hq = (lane < 4) ? (cq0 - QPAD + lane) : (cq0 + CQ + (lane - 4));
    const bool hq_ok = (lane < 8) && (hq >= 0) && (hq < NQROW);
    const int hslot = (lane < 4) ? lane : (CQ + QPAD + (lane - 4));

    auto ld_row = [&](int step, float4& m, float4& h) {
        m = Z4; h = Z4;
        const int yy = r0 - PADK + step;
        if (step < NSTEPS && yy >= 0 && yy < HH) {
            const float4* rp = targ4 + (size_t)yy * NQROW;
            m = rp[cq0 + lane];
            if (hq_ok) h = rp[hq];
        }
    };

    float vacc0 = 0.f, vacc1 = 0.f, vacc2 = 0.f, vacc3 = 0.f;
    float a_bce = 0.f, a_w = 0.f, a_i = 0.f, a_u = 0.f;
    int slot = 0;

    float4 e_p0, e_p1, h_p0, h_p1;
    ld_row(0, e_p0, h_p0);
    ld_row(1, e_p1, h_p1);
    float4 t_p0 = Z4, t_p1 = Z4, p_p0 = Z4, p_p1 = Z4;

    for (int step = 0; step < NSTEPS; ++step) {
        const float4 e  = e_p0;  e_p0 = e_p1;
        const float4 eh = h_p0;  h_p0 = h_p1;
        ld_row(step + 2, e_p1, h_p1);

        const float4 tcur = t_p0, pcur = p_p0;
        t_p0 = t_p1; p_p0 = p_p1;
        {
            const int s2 = step + 2;
            if (s2 >= 2 * PADK && s2 < NSTEPS) {
                const size_t off = (size_t)(r0 + (s2 - 2 * PADK)) * NQROW + cq0 + lane;
                t_p1 = targ4[off];
                p_p1 = pred4[off];
            }
        }

        const int bf = step & 1;
        ebuf[bf][QPAD + lane] = e;
        locq[bf][QPAD + lane] = e.x + e.y + e.z + e.w;
        if (lane < 8) {
            ebuf[bf][hslot] = eh;
            locq[bf][hslot] = eh.x + eh.y + eh.z + eh.w;
        }
        __builtin_amdgcn_wave_barrier();

        float F = 0.f;
        #pragma unroll
        for (int k = -3; k <= 3; ++k) F += locq[bf][lane + QPAD + k];
        const float4 L = ebuf[bf][lane];
        const float4 U = ebuf[bf][lane + 2 * QPAD];
        const float h0 = F + L.y + L.z + L.w;
        const float h1 = F + L.z + L.w + U.x;
        const float h2 = F + L.w + U.x + U.y;
        const float h3 = F + U.x + U.y + U.z;

        const __half2 n01 = __floats2half2_rn(h0, h1);
        const __half2 n23 = __floats2half2_rn(h2, h3);
        const __half2 o01 = ring[slot][0][lane];
        const __half2 o23 = ring[slot][1][lane];
        ring[slot][0][lane] = n01;
        ring[slot][1][lane] = n23;
        const float2 nf01 = __half22float2(n01), nf23 = __half22float2(n23);
        const float2 of01 = __half22float2(o01), of23 = __half22float2(o23);
        vacc0 += nf01.x - of01.x;
        vacc1 += nf01.y - of01.y;
        vacc2 += nf23.x - of23.x;
        vacc3 += nf23.y - of23.y;
        slot = (slot == 30) ? 0 : (slot + 1);

        if (step >= 2 * PADK) {
            elemwise4(vacc0, vacc1, vacc2, vacc3, tcur, pcur, a_bce, a_w, a_i, a_u);
        }
    }

    #pragma unroll
    for (int off = 32; off > 0; off >>= 1) {
        a_bce += __shfl_down(a_bce, off, 64);
        a_w   += __shfl_down(a_w,   off, 64);
        a_i   += __shfl_down(a_i,   off, 64);
        a_u   += __shfl_down(a_u,   off, 64);
    }
    if (lane == 0) {
        atomicAdd(&ws[0],      a_bce);
        atomicAdd(&ws[1 + b],  a_w);
        atomicAdd(&ws[33 + b], a_i);
        atomicAdd(&ws[65 + b], a_u);
    }
}

__global__ void finalize_kernel(const float* __restrict__ ws, float* __restrict__ out)
{
    const int i = threadIdx.x;
    float val = 0.f;
    if (i < BB) {
        const float bce   = ws[0] * (1.0f / NPIX_F);
        const float wsum  = ws[1 + i];
        const float inter = ws[33 + i];
        const float uni   = ws[65 + i];
        const float w_bce = (wsum * bce + 1e-8f) / (wsum + 1e-8f);
        const float w_iou = 1.0f - (inter + 1.0f + 1e-8f) / (uni - inter + 1.0f + 1e-8f);
        val = w_bce + w_iou;
    }
    #pragma unroll
    for (int off = 32; off > 0; off >>= 1) val += __shfl_down(val, off, 64);
    if (i == 0) out[0] = val * (1.0f / BB);
}

extern "C" void kernel_launch(void* const* d_in, const int* in_sizes, int n_in,
                              void* d_out, int out_size, void* d_ws, size_t ws_size,
                              hipStream_t stream)
{
    (void)in_sizes; (void)n_in; (void)out_size;
    const float* pred = (const float*)d_in[0];   // y_pred
    const float* targ = (const float*)d_in[1];   // y_target
    float* out = (float*)d_out;

    if (ws_size >= WS_NEED2) {
        float4* part = (float4*)((char*)d_ws + PART_OFF);
        __half* H = (__half*)((char*)d_ws + H_OFF);
        hipLaunchKernelGGL(hsum_kernel, dim3(NB_A), dim3(64), 0, stream,
                           targ, H);
        hipLaunchKernelGGL(vsum_loss_kernel, dim3(NB_B), dim3(64), 0, stream,
                           pred, targ, H, part);
        hipLaunchKernelGGL(finalize4_kernel, dim3(1), dim3(1024), 0, stream,
                           part, out);
    } else {
        float* ws = (float*)d_ws;
        hipMemsetAsync(ws, 0, 97 * sizeof(float), stream);
        hipLaunchKernelGGL(fused_pool_loss_kernel,
                           dim3(BB * NSTRIPES * NCH), dim3(64), 0, stream,
                           pred, targ, ws);
        hipLaunchKernelGGL(finalize_kernel, dim3(1), dim3(64), 0, stream, ws, out);
    }
}